// Round 1
// baseline (329.479 us; speedup 1.0000x reference)
//
#include <hip/hip_runtime.h>

typedef __attribute__((ext_vector_type(8))) short short8;
typedef __attribute__((ext_vector_type(4))) float f32x4;

#define DEVI static __device__ __forceinline__

constexpr int BB = 2, SS = 2048, DD = 1024, HH = 16, DKK = 64;
constexpr size_t QN = (size_t)BB * SS * DD;  // 4194304 elems
constexpr size_t WN = (size_t)DD * DD;       // 1048576 elems

// workspace layout (units: ushort/bf16 elements)
constexpr size_t OFF_QB = 0;
constexpr size_t OFF_KB = QN;
constexpr size_t OFF_VB = 2 * QN;
constexpr size_t OFF_WQ = 3 * QN;
constexpr size_t OFF_WK = OFF_WQ + WN;
constexpr size_t OFF_WV = OFF_WQ + 2 * WN;
constexpr size_t OFF_WO = OFF_WQ + 3 * WN;
constexpr size_t OFF_QM = OFF_WQ + 4 * WN;  // Q  [B,H,S,DK]
constexpr size_t OFF_KM = OFF_QM + QN;      // K  [B,H,S,DK]
constexpr size_t OFF_VM = OFF_QM + 2 * QN;  // V  [B,H,S,DK]
constexpr size_t OFF_VT = OFF_QM + 3 * QN;  // V^T [B,H,DK,S]
constexpr size_t OFF_XC = OFF_QM + 4 * QN;  // attn out [B,S,D]
// total = 37748736 ushorts = 72 MiB

DEVI unsigned short f2bf(float f) {  // fp32 -> bf16 RNE
  unsigned int u = __float_as_uint(f);
  u = (u + 0x7fffu + ((u >> 16) & 1u)) >> 16;
  return (unsigned short)u;
}

DEVI f32x4 fzero() { f32x4 z = {0.f, 0.f, 0.f, 0.f}; return z; }

// async global->LDS, 16B per lane; LDS side is wave-uniform base + lane*16
DEVI void gld16(const void* g, void* l) {
  __builtin_amdgcn_global_load_lds((__attribute__((address_space(1))) void*)g,
                                   (__attribute__((address_space(3))) void*)l,
                                   16, 0, 0);
}

// ---------------------------------------------------------------------------
// Kernel 0: fp32 -> bf16 conversion for q,k,v and the four weights
// ---------------------------------------------------------------------------
__global__ __launch_bounds__(256) void convert_all(
    const float* __restrict__ q, const float* __restrict__ k,
    const float* __restrict__ v, const float* __restrict__ wq,
    const float* __restrict__ wk, const float* __restrict__ wv,
    const float* __restrict__ wo, unsigned short* __restrict__ ws) {
  size_t t = (size_t)blockIdx.x * 256 + threadIdx.x;
  size_t e = t * 4;
  const float* src;
  size_t base, idx;
  if (e < 3 * QN) {
    size_t a = e >> 22;            // QN = 2^22
    idx = e & (QN - 1);
    src = (a == 0) ? q : (a == 1) ? k : v;
    base = a * QN;
  } else {
    size_t r = e - 3 * QN;
    size_t a = r >> 20;            // WN = 2^20
    idx = r & (WN - 1);
    src = (a == 0) ? wq : (a == 1) ? wk : (a == 2) ? wv : wo;
    base = 3 * QN + a * WN;
  }
  float4 f = *(const float4*)(src + idx);
  ushort4 o;
  o.x = f2bf(f.x); o.y = f2bf(f.y); o.z = f2bf(f.z); o.w = f2bf(f.w);
  *(ushort4*)(ws + base + idx) = o;
}

// ---------------------------------------------------------------------------
// Shared GEMM core: C[128x128] = A[128xK] * B[128xK]^T  (both operands [rows][K])
// 256 thr = 4 waves, wave -> 64x64, 4x4 grid of 16x16x32 bf16 MFMA.
// LDS tiles staged in MFMA-fragment order via global_load_lds(16B):
//   sub-tile s = rowTile*2 + kHalf, 1KB; slot l holds Op[row16+l&15][k32+(l>>4)*8..+7]
// -> ds_read_b128 is fully contiguous per wave (conflict-free).
// ---------------------------------------------------------------------------
DEVI void gemm_tile(const unsigned short* __restrict__ A,
                    const unsigned short* __restrict__ Bw,
                    unsigned short* ldsA, unsigned short* ldsB,
                    int m0, int n0, f32x4 acc[4][4]) {
  const int tid = threadIdx.x;
  const int w = tid >> 6, l = tid & 63;
  const int lr = l & 15, qd = l >> 4;
  const int wr = w >> 1, wc = w & 1;

#pragma unroll
  for (int i = 0; i < 4; ++i)
#pragma unroll
    for (int j = 0; j < 4; ++j) acc[i][j] = fzero();

  const unsigned short* pa[4];
  const unsigned short* pb[4];
  unsigned short* la[4];
  unsigned short* lb[4];
#pragma unroll
  for (int u = 0; u < 4; ++u) {
    int s = w * 4 + u;
    int t16 = s >> 1, kt = s & 1;
    pa[u] = A + (size_t)(m0 + t16 * 16 + lr) * DD + kt * 32 + qd * 8;
    pb[u] = Bw + (size_t)(n0 + t16 * 16 + lr) * DD + kt * 32 + qd * 8;
    la[u] = ldsA + s * 512;
    lb[u] = ldsB + s * 512;
  }

  for (int k0 = 0; k0 < DD; k0 += 64) {
    __syncthreads();
#pragma unroll
    for (int u = 0; u < 4; ++u) gld16(pa[u] + k0, la[u]);
#pragma unroll
    for (int u = 0; u < 4; ++u) gld16(pb[u] + k0, lb[u]);
    __syncthreads();
#pragma unroll
    for (int ks = 0; ks < 2; ++ks) {
      short8 af[4], bf[4];
#pragma unroll
      for (int im = 0; im < 4; ++im)
        af[im] = *(const short8*)&ldsA[((wr * 4 + im) * 2 + ks) * 512 + l * 8];
#pragma unroll
      for (int in = 0; in < 4; ++in)
        bf[in] = *(const short8*)&ldsB[((wc * 4 + in) * 2 + ks) * 512 + l * 8];
#pragma unroll
      for (int im = 0; im < 4; ++im)
#pragma unroll
        for (int in = 0; in < 4; ++in)
          acc[im][in] = __builtin_amdgcn_mfma_f32_16x16x32_bf16(
              af[im], bf[in], acc[im][in], 0, 0, 0);
    }
  }
}

// ---------------------------------------------------------------------------
// Kernel 1: Q/K/V projections (z picks which). Writes bf16 [B,H,S,DK].
// ---------------------------------------------------------------------------
__global__ __launch_bounds__(256) void proj_gemm(unsigned short* __restrict__ ws) {
  __shared__ unsigned short ldsA[8192];
  __shared__ unsigned short ldsB[8192];
  const int z = blockIdx.z;
  const unsigned short* A = ws + (size_t)z * QN;        // qb,kb,vb
  const unsigned short* W = ws + OFF_WQ + (size_t)z * WN;
  unsigned short* O = ws + OFF_QM + (size_t)z * QN;     // Qm,Km,Vm
  const int m0 = blockIdx.x * 128, n0 = blockIdx.y * 128;
  f32x4 acc[4][4];
  gemm_tile(A, W, ldsA, ldsB, m0, n0, acc);

  const int tid = threadIdx.x;
  const int w = tid >> 6, l = tid & 63, lr = l & 15, qd = l >> 4;
  const int wr = w >> 1, wc = w & 1;
#pragma unroll
  for (int im = 0; im < 4; ++im)
#pragma unroll
    for (int in = 0; in < 4; ++in) {
      const int n = n0 + wc * 64 + in * 16 + lr;
      const int h = n >> 6, dk = n & 63;
#pragma unroll
      for (int i = 0; i < 4; ++i) {
        const int m = m0 + wr * 64 + im * 16 + qd * 4 + i;
        const int b = m >> 11, s = m & 2047;
        O[((size_t)(b * HH + h) * SS + s) * DKK + dk] = f2bf(acc[im][in][i]);
      }
    }
}

// ---------------------------------------------------------------------------
// Kernel 2: V [B,H,S,DK] -> V^T [B,H,DK,S]
// ---------------------------------------------------------------------------
__global__ __launch_bounds__(256) void transpose_v(
    const unsigned short* __restrict__ Vm, unsigned short* __restrict__ Vt) {
  __shared__ unsigned short t[64][72];  // +8 pad keeps 16B alignment, breaks conflicts
  const int s0 = blockIdx.x * 64;
  const int h = blockIdx.y, b = blockIdx.z;
  const unsigned short* src = Vm + (size_t)(b * HH + h) * SS * DKK;
  unsigned short* dstb = Vt + (size_t)(b * HH + h) * DKK * SS;
  const int tid = threadIdx.x;
  const int r = tid >> 2;
#pragma unroll
  for (int half = 0; half < 2; ++half) {
    const int c = ((tid & 3) + half * 4) * 8;
    *(uint4*)&t[r][c] = *(const uint4*)&src[(size_t)(s0 + r) * DKK + c];
  }
  __syncthreads();
  const int dk = tid >> 2, scc = (tid & 3) * 16;
  alignas(16) unsigned short tmp[16];
#pragma unroll
  for (int j = 0; j < 16; ++j) tmp[j] = t[scc + j][dk];
  unsigned short* dst = dstb + (size_t)dk * SS + s0 + scc;
  *(uint4*)&dst[0] = *(const uint4*)&tmp[0];
  *(uint4*)&dst[8] = *(const uint4*)&tmp[8];
}

// ---------------------------------------------------------------------------
// Kernel 3: causal flash attention. Block = (b, h, 64 q-rows), 4 waves x 16 rows.
// ---------------------------------------------------------------------------
__global__ __launch_bounds__(256) void flash_attn(
    const unsigned short* __restrict__ Qm, const unsigned short* __restrict__ Km,
    const unsigned short* __restrict__ Vt, unsigned short* __restrict__ Xc) {
  __shared__ unsigned short Kl[4096];  // K-tile, fragment order (B-operand of QK^T)
  __shared__ unsigned short Vl[4096];  // V^T-tile, fragment order (B-operand of PV)
  __shared__ unsigned short Pl[4096];  // P round-trip, 1K ushorts per wave
  const int qt = (int)gridDim.x - 1 - (int)blockIdx.x;  // heavy tiles first
  const int h = blockIdx.y, b = blockIdx.z;
  const int tid = threadIdx.x, w = tid >> 6, l = tid & 63, lr = l & 15, qd = l >> 4;
  const int q0 = qt * 64;
  const size_t bh = (size_t)(b * HH + h);
  const unsigned short* Qb = Qm + bh * SS * DKK;
  const unsigned short* Kb = Km + bh * SS * DKK;
  const unsigned short* Vb = Vt + bh * DKK * SS;

  // Q fragments for this wave's 16 rows (A-operand layout)
  const int qrow = q0 + w * 16 + lr;
  short8 qf0 = *(const short8*)&Qb[(size_t)qrow * DKK + qd * 8];
  short8 qf1 = *(const short8*)&Qb[(size_t)qrow * DKK + 32 + qd * 8];

  f32x4 o[4];
#pragma unroll
  for (int i = 0; i < 4; ++i) o[i] = fzero();
  float mrow[4] = {-3e38f, -3e38f, -3e38f, -3e38f};
  float lrow[4] = {0.f, 0.f, 0.f, 0.f};
  unsigned short* Pw = &Pl[w * 1024];

  const int nkv = qt + 1;
  for (int kv = 0; kv < nkv; ++kv) {
    const int kv0 = kv * 64;
    __syncthreads();  // prior iteration's LDS reads complete
#pragma unroll
    for (int u = 0; u < 2; ++u) {
      const int sK = w + u * 4;  // each wave stages 2 of 8 sub-tiles of each
      const int nt = sK >> 1, ks = sK & 1;
      gld16(&Kb[(size_t)(kv0 + nt * 16 + lr) * DKK + ks * 32 + qd * 8], &Kl[sK * 512]);
      const int kt2 = sK >> 2, nt2 = sK & 3;
      gld16(&Vb[(size_t)(nt2 * 16 + lr) * SS + kv0 + kt2 * 32 + qd * 8], &Vl[sK * 512]);
    }
    __syncthreads();  // staging visible (compiler emits vmcnt(0) drain)

    // S = Q K^T / 8 : 16 rows x 64 cols in 4 C-frags
    f32x4 sc[4];
#pragma unroll
    for (int nt = 0; nt < 4; ++nt) {
      short8 kf0 = *(const short8*)&Kl[(nt * 2 + 0) * 512 + l * 8];
      short8 kf1 = *(const short8*)&Kl[(nt * 2 + 1) * 512 + l * 8];
      f32x4 zz = fzero();
      zz = __builtin_amdgcn_mfma_f32_16x16x32_bf16(qf0, kf0, zz, 0, 0, 0);
      sc[nt] = __builtin_amdgcn_mfma_f32_16x16x32_bf16(qf1, kf1, zz, 0, 0, 0);
    }
    const bool diag = (kv == qt);
#pragma unroll
    for (int nt = 0; nt < 4; ++nt)
#pragma unroll
      for (int i = 0; i < 4; ++i) {
        float vv = sc[nt][i] * 0.125f;  // 1/sqrt(64)
        if (diag) {
          const int col = kv0 + nt * 16 + lr;
          const int row = q0 + w * 16 + qd * 4 + i;
          if (col > row) vv = -3e38f;
        }
        sc[nt][i] = vv;
      }

    // online softmax; row r = qd*4+i lives in the 16 lanes of this quad
#pragma unroll
    for (int i = 0; i < 4; ++i) {
      float mx = fmaxf(fmaxf(sc[0][i], sc[1][i]), fmaxf(sc[2][i], sc[3][i]));
#pragma unroll
      for (int d = 1; d < 16; d <<= 1) mx = fmaxf(mx, __shfl_xor(mx, d));
      const float mnew = fmaxf(mrow[i], mx);
      const float alpha = __expf(mrow[i] - mnew);
      mrow[i] = mnew;
      float rs = 0.f;
#pragma unroll
      for (int nt = 0; nt < 4; ++nt) {
        const float p = __expf(sc[nt][i] - mnew);
        sc[nt][i] = p;
        rs += p;
      }
#pragma unroll
      for (int d = 1; d < 16; d <<= 1) rs += __shfl_xor(rs, d);
      lrow[i] = lrow[i] * alpha + rs;
#pragma unroll
      for (int nt2 = 0; nt2 < 4; ++nt2) o[nt2][i] *= alpha;
    }

    // P: C-layout -> A-operand layout via wave-private LDS
    // element (r=qd*4+i, c=nt*16+lr) -> idx (c>>5)*512 + (((c>>3)&3)*16+r)*8 + (c&7)
#pragma unroll
    for (int nt = 0; nt < 4; ++nt) {
      const int hi = (nt * 2 + (lr >> 3)) & 3;
#pragma unroll
      for (int i = 0; i < 4; ++i) {
        const int idx = (nt >> 1) * 512 + hi * 128 + (qd * 4 + i) * 8 + (lr & 7);
        Pw[idx] = f2bf(sc[nt][i]);
      }
    }
    // O += P V  (A-frag from Pw, B-frag from Vl; lgkmcnt wait auto-inserted)
#pragma unroll
    for (int kt2 = 0; kt2 < 2; ++kt2) {
      short8 pf = *(const short8*)&Pw[kt2 * 512 + l * 8];
#pragma unroll
      for (int nt2 = 0; nt2 < 4; ++nt2) {
        short8 vf = *(const short8*)&Vl[(kt2 * 4 + nt2) * 512 + l * 8];
        o[nt2] = __builtin_amdgcn_mfma_f32_16x16x32_bf16(pf, vf, o[nt2], 0, 0, 0);
      }
    }
  }

  // normalize and write bf16 [B,S,D]
#pragma unroll
  for (int i = 0; i < 4; ++i) {
    const float inv = 1.0f / lrow[i];
    const int srow = q0 + w * 16 + qd * 4 + i;
    const size_t base = ((size_t)b * SS + srow) * DD + (size_t)h * DKK;
#pragma unroll
    for (int nt2 = 0; nt2 < 4; ++nt2)
      Xc[base + nt2 * 16 + lr] = f2bf(o[nt2][i] * inv);
  }
}

// ---------------------------------------------------------------------------
// Kernel 4: out = Xc @ w_o^T, fp32 epilogue straight to d_out
// ---------------------------------------------------------------------------
__global__ __launch_bounds__(256) void out_gemm(
    const unsigned short* __restrict__ Xc, const unsigned short* __restrict__ Wo,
    float* __restrict__ out) {
  __shared__ unsigned short ldsA[8192];
  __shared__ unsigned short ldsB[8192];
  const int m0 = blockIdx.x * 128, n0 = blockIdx.y * 128;
  f32x4 acc[4][4];
  gemm_tile(Xc, Wo, ldsA, ldsB, m0, n0, acc);

  const int tid = threadIdx.x;
  const int w = tid >> 6, l = tid & 63, lr = l & 15, qd = l >> 4;
  const int wr = w >> 1, wc = w & 1;
#pragma unroll
  for (int im = 0; im < 4; ++im)
#pragma unroll
    for (int in = 0; in < 4; ++in) {
      const int n = n0 + wc * 64 + in * 16 + lr;
#pragma unroll
      for (int i = 0; i < 4; ++i) {
        const int m = m0 + wr * 64 + im * 16 + qd * 4 + i;
        out[(size_t)m * DD + n] = acc[im][in][i];
      }
    }
}

// ---------------------------------------------------------------------------
extern "C" void kernel_launch(void* const* d_in, const int* in_sizes, int n_in,
                              void* d_out, int out_size, void* d_ws, size_t ws_size,
                              hipStream_t stream) {
  (void)in_sizes; (void)n_in; (void)out_size; (void)ws_size;
  const float* q  = (const float*)d_in[0];
  const float* k  = (const float*)d_in[1];
  const float* v  = (const float*)d_in[2];
  // d_in[3] = causal mask, structure known -> unused
  const float* wq = (const float*)d_in[4];
  const float* wk = (const float*)d_in[5];
  const float* wv = (const float*)d_in[6];
  const float* wo = (const float*)d_in[7];
  unsigned short* ws = (unsigned short*)d_ws;
  float* out = (float*)d_out;

  convert_all<<<dim3(16384), dim3(256), 0, stream>>>(q, k, v, wq, wk, wv, wo, ws);
  proj_gemm<<<dim3(32, 8, 3), dim3(256), 0, stream>>>(ws);
  transpose_v<<<dim3(32, 16, 2), dim3(256), 0, stream>>>(ws + OFF_VM, ws + OFF_VT);
  flash_attn<<<dim3(32, 16, 2), dim3(256), 0, stream>>>(ws + OFF_QM, ws + OFF_KM,
                                                        ws + OFF_VT, ws + OFF_XC);
  out_gemm<<<dim3(32, 8), dim3(256), 0, stream>>>(ws + OFF_XC, ws + OFF_WO, out);
}

// Round 3
// 291.560 us; speedup vs baseline: 1.1301x; 1.1301x over previous
//
#include <hip/hip_runtime.h>

typedef __attribute__((ext_vector_type(8))) short short8;
typedef __attribute__((ext_vector_type(4))) float f32x4;

#define DEVI static __device__ __forceinline__

constexpr int BB = 2, SS = 2048, DD = 1024, HH = 16, DKK = 64;
constexpr size_t QN = (size_t)BB * SS * DD;  // 4194304 elems
constexpr size_t WN = (size_t)DD * DD;       // 1048576 elems

// workspace layout (units: ushort/bf16 elements)
constexpr size_t OFF_WQ = 3 * QN;
constexpr size_t OFF_WO = OFF_WQ + 3 * WN;
constexpr size_t OFF_QM = OFF_WQ + 4 * WN;  // Q   [B,H,S,DK]
constexpr size_t OFF_KM = OFF_QM + QN;      // K   [B,H,S,DK]
constexpr size_t OFF_VM = OFF_QM + 2 * QN;  // V^T [B,H,DK,S] (written directly by proj)
constexpr size_t OFF_XC = OFF_QM + 3 * QN;  // attn out [B,S,D]

DEVI unsigned short f2bf(float f) {  // fp32 -> bf16 RNE
  unsigned int u = __float_as_uint(f);
  u = (u + 0x7fffu + ((u >> 16) & 1u)) >> 16;
  return (unsigned short)u;
}

DEVI f32x4 fzero() { f32x4 z = {0.f, 0.f, 0.f, 0.f}; return z; }

DEVI void gld16(const void* g, void* l) {
  __builtin_amdgcn_global_load_lds((__attribute__((address_space(1))) void*)g,
                                   (__attribute__((address_space(3))) void*)l,
                                   16, 0, 0);
}

// ---------------------------------------------------------------------------
// Kernel 0: fp32 -> bf16 conversion for q,k,v and the four weights
// ---------------------------------------------------------------------------
__global__ __launch_bounds__(256) void convert_all(
    const float* __restrict__ q, const float* __restrict__ k,
    const float* __restrict__ v, const float* __restrict__ wq,
    const float* __restrict__ wk, const float* __restrict__ wv,
    const float* __restrict__ wo, unsigned short* __restrict__ ws) {
  size_t t = (size_t)blockIdx.x * 256 + threadIdx.x;
  size_t e = t * 4;
  const float* src;
  size_t base, idx;
  if (e < 3 * QN) {
    size_t a = e >> 22;            // QN = 2^22
    idx = e & (QN - 1);
    src = (a == 0) ? q : (a == 1) ? k : v;
    base = a * QN;
  } else {
    size_t r = e - 3 * QN;
    size_t a = r >> 20;            // WN = 2^20
    idx = r & (WN - 1);
    src = (a == 0) ? wq : (a == 1) ? wk : (a == 2) ? wv : wo;
    base = 3 * QN + a * WN;
  }
  float4 f = *(const float4*)(src + idx);
  ushort4 o;
  o.x = f2bf(f.x); o.y = f2bf(f.y); o.z = f2bf(f.z); o.w = f2bf(f.w);
  *(ushort4*)(ws + base + idx) = o;
}

// ---------------------------------------------------------------------------
// Shared GEMM core: C[128x128] = A[128xK] * B[128xK]^T  (both operands [rows][K])
// ---------------------------------------------------------------------------
DEVI void gemm_tile(const unsigned short* __restrict__ A,
                    const unsigned short* __restrict__ Bw,
                    unsigned short* ldsA, unsigned short* ldsB,
                    int m0, int n0, f32x4 acc[4][4]) {
  const int tid = threadIdx.x;
  const int w = tid >> 6, l = tid & 63;
  const int lr = l & 15, qd = l >> 4;
  const int wr = w >> 1, wc = w & 1;

#pragma unroll
  for (int i = 0; i < 4; ++i)
#pragma unroll
    for (int j = 0; j < 4; ++j) acc[i][j] = fzero();

  const unsigned short* pa[4];
  const unsigned short* pb[4];
  unsigned short* la[4];
  unsigned short* lb[4];
#pragma unroll
  for (int u = 0; u < 4; ++u) {
    int s = w * 4 + u;
    int t16 = s >> 1, kt = s & 1;
    pa[u] = A + (size_t)(m0 + t16 * 16 + lr) * DD + kt * 32 + qd * 8;
    pb[u] = Bw + (size_t)(n0 + t16 * 16 + lr) * DD + kt * 32 + qd * 8;
    la[u] = ldsA + s * 512;
    lb[u] = ldsB + s * 512;
  }

  for (int k0 = 0; k0 < DD; k0 += 64) {
    __syncthreads();
#pragma unroll
    for (int u = 0; u < 4; ++u) gld16(pa[u] + k0, la[u]);
#pragma unroll
    for (int u = 0; u < 4; ++u) gld16(pb[u] + k0, lb[u]);
    __syncthreads();
#pragma unroll
    for (int ks = 0; ks < 2; ++ks) {
      short8 af[4], bf[4];
#pragma unroll
      for (int im = 0; im < 4; ++im)
        af[im] = *(const short8*)&ldsA[((wr * 4 + im) * 2 + ks) * 512 + l * 8];
#pragma unroll
      for (int in = 0; in < 4; ++in)
        bf[in] = *(const short8*)&ldsB[((wc * 4 + in) * 2 + ks) * 512 + l * 8];
#pragma unroll
      for (int im = 0; im < 4; ++im)
#pragma unroll
        for (int in = 0; in < 4; ++in)
          acc[im][in] = __builtin_amdgcn_mfma_f32_16x16x32_bf16(
              af[im], bf[in], acc[im][in], 0, 0, 0);
    }
  }
}

// ---------------------------------------------------------------------------
// Kernel 1: Q/K/V projections. z=0,1 write [B,H,S,DK]; z=2 writes V^T [B,H,DK,S].
// ---------------------------------------------------------------------------
__global__ __launch_bounds__(256) void proj_gemm(unsigned short* __restrict__ ws) {
  __shared__ unsigned short ldsA[8192];
  __shared__ unsigned short ldsB[8192];
  const int z = blockIdx.z;
  const unsigned short* A = ws + (size_t)z * QN;
  const unsigned short* W = ws + OFF_WQ + (size_t)z * WN;
  unsigned short* O = ws + OFF_QM + (size_t)z * QN;
  const int m0 = blockIdx.x * 128, n0 = blockIdx.y * 128;
  f32x4 acc[4][4];
  gemm_tile(A, W, ldsA, ldsB, m0, n0, acc);

  const int tid = threadIdx.x;
  const int w = tid >> 6, l = tid & 63, lr = l & 15, qd = l >> 4;
  const int wr = w >> 1, wc = w & 1;
  if (z == 2) {
    // V^T: 4 consecutive s per (im,in) pack into one 8-byte store
#pragma unroll
    for (int im = 0; im < 4; ++im)
#pragma unroll
      for (int in = 0; in < 4; ++in) {
        const int n = n0 + wc * 64 + in * 16 + lr;
        const int h = n >> 6, dk = n & 63;
        const int m = m0 + wr * 64 + im * 16 + qd * 4;
        const int b = m >> 11, s = m & 2047;
        ushort4 pk;
        pk.x = f2bf(acc[im][in][0]); pk.y = f2bf(acc[im][in][1]);
        pk.z = f2bf(acc[im][in][2]); pk.w = f2bf(acc[im][in][3]);
        *(ushort4*)&O[((size_t)(b * HH + h) * DKK + dk) * SS + s] = pk;
      }
  } else {
#pragma unroll
    for (int im = 0; im < 4; ++im)
#pragma unroll
      for (int in = 0; in < 4; ++in) {
        const int n = n0 + wc * 64 + in * 16 + lr;
        const int h = n >> 6, dk = n & 63;
#pragma unroll
        for (int i = 0; i < 4; ++i) {
          const int m = m0 + wr * 64 + im * 16 + qd * 4 + i;
          const int b = m >> 11, s = m & 2047;
          O[((size_t)(b * HH + h) * SS + s) * DKK + dk] = f2bf(acc[im][in][i]);
        }
      }
  }
}

// ---------------------------------------------------------------------------
// Kernel 2: causal flash attention, pair-balanced + double-buffered prefetch.
// Block = (pair p, h, b): q-tiles p and 31-p -> exactly 33 kv-iters per block.
// ---------------------------------------------------------------------------
__global__ __launch_bounds__(256) void flash_attn(
    const unsigned short* __restrict__ Qm, const unsigned short* __restrict__ Km,
    const unsigned short* __restrict__ Vt, unsigned short* __restrict__ Xc) {
  __shared__ unsigned short Kl[2][4096];
  __shared__ unsigned short Vl[2][4096];
  __shared__ unsigned short Pl[4096];
  const int p = blockIdx.x, h = blockIdx.y, b = blockIdx.z;
  const int tid = threadIdx.x, w = tid >> 6, l = tid & 63, lr = l & 15, qd = l >> 4;
  const size_t bh = (size_t)(b * HH + h);
  const unsigned short* Qb = Qm + bh * SS * DKK;
  const unsigned short* Kb = Km + bh * SS * DKK;
  const unsigned short* Vb = Vt + bh * DKK * SS;
  unsigned short* Pw = &Pl[w * 1024];

  // this wave's 2-of-8 staging sub-tiles
  const int sK0 = w, sK1 = w + 4;

#pragma unroll 1
  for (int si = 0; si < 2; ++si) {
    const int qt = si ? (31 - p) : p;
    const int q0 = qt * 64;
    const int nkv = qt + 1;

    const int qrow = q0 + w * 16 + lr;
    short8 qf0 = *(const short8*)&Qb[(size_t)qrow * DKK + qd * 8];
    short8 qf1 = *(const short8*)&Qb[(size_t)qrow * DKK + 32 + qd * 8];

    f32x4 o[4];
#pragma unroll
    for (int i = 0; i < 4; ++i) o[i] = fzero();
    float mrow[4] = {-3e38f, -3e38f, -3e38f, -3e38f};
    float lrow[4] = {0.f, 0.f, 0.f, 0.f};

    __syncthreads();  // prior segment's LDS reads complete before buf0 overwrite
    // prefetch kv=0 -> buf0
    {
      const int nt = sK0 >> 1, ks = sK0 & 1;
      gld16(&Kb[(size_t)(nt * 16 + lr) * DKK + ks * 32 + qd * 8], &Kl[0][sK0 * 512]);
      const int ntb = sK1 >> 1, ksb = sK1 & 1;
      gld16(&Kb[(size_t)(ntb * 16 + lr) * DKK + ksb * 32 + qd * 8], &Kl[0][sK1 * 512]);
      const int kt2 = sK0 >> 2, nt2 = sK0 & 3;
      gld16(&Vb[(size_t)(nt2 * 16 + lr) * SS + kt2 * 32 + qd * 8], &Vl[0][sK0 * 512]);
      const int kt2b = sK1 >> 2, nt2b = sK1 & 3;
      gld16(&Vb[(size_t)(nt2b * 16 + lr) * SS + kt2b * 32 + qd * 8], &Vl[0][sK1 * 512]);
    }

#pragma unroll 1
    for (int kv = 0; kv < nkv; ++kv) {
      __syncthreads();  // drains prefetch(kv); fences buf reuse
      const int cur = kv & 1;
      if (kv + 1 < nkv) {  // prefetch kv+1 into the other buffer
        const int kv0n = (kv + 1) * 64;
        const int nt = sK0 >> 1, ks = sK0 & 1;
        gld16(&Kb[(size_t)(kv0n + nt * 16 + lr) * DKK + ks * 32 + qd * 8],
              &Kl[cur ^ 1][sK0 * 512]);
        const int ntb = sK1 >> 1, ksb = sK1 & 1;
        gld16(&Kb[(size_t)(kv0n + ntb * 16 + lr) * DKK + ksb * 32 + qd * 8],
              &Kl[cur ^ 1][sK1 * 512]);
        const int kt2 = sK0 >> 2, nt2 = sK0 & 3;
        gld16(&Vb[(size_t)(nt2 * 16 + lr) * SS + kv0n + kt2 * 32 + qd * 8],
              &Vl[cur ^ 1][sK0 * 512]);
        const int kt2b = sK1 >> 2, nt2b = sK1 & 3;
        gld16(&Vb[(size_t)(nt2b * 16 + lr) * SS + kv0n + kt2b * 32 + qd * 8],
              &Vl[cur ^ 1][sK1 * 512]);
      }

      const int kv0 = kv * 64;
      // S = Q K^T / 8
      f32x4 sc[4];
#pragma unroll
      for (int nt = 0; nt < 4; ++nt) {
        short8 kf0 = *(const short8*)&Kl[cur][(nt * 2 + 0) * 512 + l * 8];
        short8 kf1 = *(const short8*)&Kl[cur][(nt * 2 + 1) * 512 + l * 8];
        f32x4 zz = fzero();
        zz = __builtin_amdgcn_mfma_f32_16x16x32_bf16(qf0, kf0, zz, 0, 0, 0);
        sc[nt] = __builtin_amdgcn_mfma_f32_16x16x32_bf16(qf1, kf1, zz, 0, 0, 0);
      }
      const bool diag = (kv == qt);
#pragma unroll
      for (int nt = 0; nt < 4; ++nt)
#pragma unroll
        for (int i = 0; i < 4; ++i) {
          float vv = sc[nt][i] * 0.125f;  // 1/sqrt(64)
          if (diag) {
            const int col = kv0 + nt * 16 + lr;
            const int row = q0 + w * 16 + qd * 4 + i;
            if (col > row) vv = -3e38f;
          }
          sc[nt][i] = vv;
        }

      // online softmax (row r = qd*4+i spread over this quad's 16 lanes)
#pragma unroll
      for (int i = 0; i < 4; ++i) {
        float mx = fmaxf(fmaxf(sc[0][i], sc[1][i]), fmaxf(sc[2][i], sc[3][i]));
#pragma unroll
        for (int d = 1; d < 16; d <<= 1) mx = fmaxf(mx, __shfl_xor(mx, d));
        const float mnew = fmaxf(mrow[i], mx);
        const float alpha = __expf(mrow[i] - mnew);
        mrow[i] = mnew;
        float rs = 0.f;
#pragma unroll
        for (int nt = 0; nt < 4; ++nt) {
          const float pp = __expf(sc[nt][i] - mnew);
          sc[nt][i] = pp;
          rs += pp;
        }
#pragma unroll
        for (int d = 1; d < 16; d <<= 1) rs += __shfl_xor(rs, d);
        lrow[i] = lrow[i] * alpha + rs;
#pragma unroll
        for (int nt2 = 0; nt2 < 4; ++nt2) o[nt2][i] *= alpha;
      }

      // P: C-layout -> A-operand layout via wave-private LDS
#pragma unroll
      for (int nt = 0; nt < 4; ++nt) {
        const int hi = (nt * 2 + (lr >> 3)) & 3;
#pragma unroll
        for (int i = 0; i < 4; ++i) {
          const int idx = (nt >> 1) * 512 + hi * 128 + (qd * 4 + i) * 8 + (lr & 7);
          Pw[idx] = f2bf(sc[nt][i]);
        }
      }
      // O += P V
#pragma unroll
      for (int kt2 = 0; kt2 < 2; ++kt2) {
        short8 pf = *(const short8*)&Pw[kt2 * 512 + l * 8];
#pragma unroll
        for (int nt2 = 0; nt2 < 4; ++nt2) {
          short8 vf = *(const short8*)&Vl[cur][(kt2 * 4 + nt2) * 512 + l * 8];
          o[nt2] = __builtin_amdgcn_mfma_f32_16x16x32_bf16(pf, vf, o[nt2], 0, 0, 0);
        }
      }
    }

    // normalize + write bf16 [B,S,D]
#pragma unroll
    for (int i = 0; i < 4; ++i) {
      const float inv = 1.0f / lrow[i];
      const int srow = q0 + w * 16 + qd * 4 + i;
      const size_t base = ((size_t)b * SS + srow) * DD + (size_t)h * DKK;
#pragma unroll
      for (int nt2 = 0; nt2 < 4; ++nt2)
        Xc[base + nt2 * 16 + lr] = f2bf(o[nt2][i] * inv);
    }
  }
}

// ---------------------------------------------------------------------------
// Kernel 3: out = Xc @ w_o^T, fp32 epilogue straight to d_out
// ---------------------------------------------------------------------------
__global__ __launch_bounds__(256) void out_gemm(
    const unsigned short* __restrict__ Xc, const unsigned short* __restrict__ Wo,
    float* __restrict__ out) {
  __shared__ unsigned short ldsA[8192];
  __shared__ unsigned short ldsB[8192];
  const int m0 = blockIdx.x * 128, n0 = blockIdx.y * 128;
  f32x4 acc[4][4];
  gemm_tile(Xc, Wo, ldsA, ldsB, m0, n0, acc);

  const int tid = threadIdx.x;
  const int w = tid >> 6, l = tid & 63, lr = l & 15, qd = l >> 4;
  const int wr = w >> 1, wc = w & 1;
#pragma unroll
  for (int im = 0; im < 4; ++im)
#pragma unroll
    for (int in = 0; in < 4; ++in) {
      const int n = n0 + wc * 64 + in * 16 + lr;
#pragma unroll
      for (int i = 0; i < 4; ++i) {
        const int m = m0 + wr * 64 + im * 16 + qd * 4 + i;
        out[(size_t)m * DD + n] = acc[im][in][i];
      }
    }
}

// ---------------------------------------------------------------------------
extern "C" void kernel_launch(void* const* d_in, const int* in_sizes, int n_in,
                              void* d_out, int out_size, void* d_ws, size_t ws_size,
                              hipStream_t stream) {
  (void)in_sizes; (void)n_in; (void)out_size; (void)ws_size;
  const float* q  = (const float*)d_in[0];
  const float* k  = (const float*)d_in[1];
  const float* v  = (const float*)d_in[2];
  const float* wq = (const float*)d_in[4];
  const float* wk = (const float*)d_in[5];
  const float* wv = (const float*)d_in[6];
  const float* wo = (const float*)d_in[7];
  unsigned short* ws = (unsigned short*)d_ws;
  float* out = (float*)d_out;

  convert_all<<<dim3(16384), dim3(256), 0, stream>>>(q, k, v, wq, wk, wv, wo, ws);
  proj_gemm<<<dim3(32, 8, 3), dim3(256), 0, stream>>>(ws);
  flash_attn<<<dim3(16, 16, 2), dim3(256), 0, stream>>>(ws + OFF_QM, ws + OFF_KM,
                                                        ws + OFF_VM, ws + OFF_XC);
  out_gemm<<<dim3(32, 8), dim3(256), 0, stream>>>(ws + OFF_XC, ws + OFF_WO, out);
}

// Round 4
// 271.238 us; speedup vs baseline: 1.2147x; 1.0749x over previous
//
#include <hip/hip_runtime.h>

typedef __attribute__((ext_vector_type(8))) short short8;
typedef __attribute__((ext_vector_type(4))) float f32x4;

#define DEVI static __device__ __forceinline__

constexpr int BB = 2, SS = 2048, DD = 1024, HH = 16, DKK = 64;
constexpr size_t QN = (size_t)BB * SS * DD;  // 4194304 elems
constexpr size_t WN = (size_t)DD * DD;       // 1048576 elems

// workspace layout (units: ushort/bf16 elements)
constexpr size_t OFF_WQ = 3 * QN;
constexpr size_t OFF_WO = OFF_WQ + 3 * WN;
constexpr size_t OFF_QM = OFF_WQ + 4 * WN;  // Q   [B,H,S,DK]
constexpr size_t OFF_KM = OFF_QM + QN;      // K   [B,H,S,DK]
constexpr size_t OFF_VM = OFF_QM + 2 * QN;  // V^T [B,H,DK,S] (written directly by proj)
constexpr size_t OFF_XC = OFF_QM + 3 * QN;  // attn out [B,S,D]

DEVI unsigned short f2bf(float f) {  // fp32 -> bf16 RNE
  unsigned int u = __float_as_uint(f);
  u = (u + 0x7fffu + ((u >> 16) & 1u)) >> 16;
  return (unsigned short)u;
}

DEVI f32x4 fzero() { f32x4 z = {0.f, 0.f, 0.f, 0.f}; return z; }

DEVI void gld16(const void* g, void* l) {
  __builtin_amdgcn_global_load_lds((__attribute__((address_space(1))) void*)g,
                                   (__attribute__((address_space(3))) void*)l,
                                   16, 0, 0);
}

DEVI short8 mk8u(unsigned int a, unsigned int b, unsigned int c, unsigned int d) {
  union { short8 s; unsigned int u[4]; } x;
  x.u[0] = a; x.u[1] = b; x.u[2] = c; x.u[3] = d;
  return x.s;
}

DEVI short8 mk8q(unsigned long long lo, unsigned long long hi) {
  union { short8 s; unsigned long long q[2]; } x;
  x.q[0] = lo; x.q[1] = hi;
  return x.s;
}

// pack two fp32 -> bf16x2 (truncate): low16 = a, high16 = b
DEVI unsigned int pkbf(float a, float b) {
  return __builtin_amdgcn_perm(__float_as_uint(b), __float_as_uint(a), 0x07060302u);
}

// ---------------------------------------------------------------------------
// Kernel 0: fp32 -> bf16 conversion for q,k,v and the four weights
// ---------------------------------------------------------------------------
__global__ __launch_bounds__(256) void convert_all(
    const float* __restrict__ q, const float* __restrict__ k,
    const float* __restrict__ v, const float* __restrict__ wq,
    const float* __restrict__ wk, const float* __restrict__ wv,
    const float* __restrict__ wo, unsigned short* __restrict__ ws) {
  size_t t = (size_t)blockIdx.x * 256 + threadIdx.x;
  size_t e = t * 4;
  const float* src;
  size_t base, idx;
  if (e < 3 * QN) {
    size_t a = e >> 22;            // QN = 2^22
    idx = e & (QN - 1);
    src = (a == 0) ? q : (a == 1) ? k : v;
    base = a * QN;
  } else {
    size_t r = e - 3 * QN;
    size_t a = r >> 20;            // WN = 2^20
    idx = r & (WN - 1);
    src = (a == 0) ? wq : (a == 1) ? wk : (a == 2) ? wv : wo;
    base = 3 * QN + a * WN;
  }
  float4 f = *(const float4*)(src + idx);
  ushort4 o;
  o.x = f2bf(f.x); o.y = f2bf(f.y); o.z = f2bf(f.z); o.w = f2bf(f.w);
  *(ushort4*)(ws + base + idx) = o;
}

// ---------------------------------------------------------------------------
// Shared GEMM core: C[128x128] = A[128xK] * B[128xK]^T  (both operands [rows][K])
// ---------------------------------------------------------------------------
DEVI void gemm_tile(const unsigned short* __restrict__ A,
                    const unsigned short* __restrict__ Bw,
                    unsigned short* ldsA, unsigned short* ldsB,
                    int m0, int n0, f32x4 acc[4][4]) {
  const int tid = threadIdx.x;
  const int w = tid >> 6, l = tid & 63;
  const int lr = l & 15, qd = l >> 4;
  const int wr = w >> 1, wc = w & 1;

#pragma unroll
  for (int i = 0; i < 4; ++i)
#pragma unroll
    for (int j = 0; j < 4; ++j) acc[i][j] = fzero();

  const unsigned short* pa[4];
  const unsigned short* pb[4];
  unsigned short* la[4];
  unsigned short* lb[4];
#pragma unroll
  for (int u = 0; u < 4; ++u) {
    int s = w * 4 + u;
    int t16 = s >> 1, kt = s & 1;
    pa[u] = A + (size_t)(m0 + t16 * 16 + lr) * DD + kt * 32 + qd * 8;
    pb[u] = Bw + (size_t)(n0 + t16 * 16 + lr) * DD + kt * 32 + qd * 8;
    la[u] = ldsA + s * 512;
    lb[u] = ldsB + s * 512;
  }

  for (int k0 = 0; k0 < DD; k0 += 64) {
    __syncthreads();
#pragma unroll
    for (int u = 0; u < 4; ++u) gld16(pa[u] + k0, la[u]);
#pragma unroll
    for (int u = 0; u < 4; ++u) gld16(pb[u] + k0, lb[u]);
    __syncthreads();
#pragma unroll
    for (int ks = 0; ks < 2; ++ks) {
      short8 af[4], bf[4];
#pragma unroll
      for (int im = 0; im < 4; ++im)
        af[im] = *(const short8*)&ldsA[((wr * 4 + im) * 2 + ks) * 512 + l * 8];
#pragma unroll
      for (int in = 0; in < 4; ++in)
        bf[in] = *(const short8*)&ldsB[((wc * 4 + in) * 2 + ks) * 512 + l * 8];
#pragma unroll
      for (int im = 0; im < 4; ++im)
#pragma unroll
        for (int in = 0; in < 4; ++in)
          acc[im][in] = __builtin_amdgcn_mfma_f32_16x16x32_bf16(
              af[im], bf[in], acc[im][in], 0, 0, 0);
    }
  }
}

// ---------------------------------------------------------------------------
// Kernel 1: Q/K/V projections. z=0,1 write [B,H,S,DK]; z=2 writes V^T [B,H,DK,S].
// ---------------------------------------------------------------------------
__global__ __launch_bounds__(256) void proj_gemm(unsigned short* __restrict__ ws) {
  __shared__ unsigned short ldsA[8192];
  __shared__ unsigned short ldsB[8192];
  const int z = blockIdx.z;
  const unsigned short* A = ws + (size_t)z * QN;
  const unsigned short* W = ws + OFF_WQ + (size_t)z * WN;
  unsigned short* O = ws + OFF_QM + (size_t)z * QN;
  const int m0 = blockIdx.x * 128, n0 = blockIdx.y * 128;
  f32x4 acc[4][4];
  gemm_tile(A, W, ldsA, ldsB, m0, n0, acc);

  const int tid = threadIdx.x;
  const int w = tid >> 6, l = tid & 63, lr = l & 15, qd = l >> 4;
  const int wr = w >> 1, wc = w & 1;
  if (z == 2) {
    // V^T: 4 consecutive s per (im,in) pack into one 8-byte store
#pragma unroll
    for (int im = 0; im < 4; ++im)
#pragma unroll
      for (int in = 0; in < 4; ++in) {
        const int n = n0 + wc * 64 + in * 16 + lr;
        const int h = n >> 6, dk = n & 63;
        const int m = m0 + wr * 64 + im * 16 + qd * 4;
        const int b = m >> 11, s = m & 2047;
        ushort4 pk;
        pk.x = f2bf(acc[im][in][0]); pk.y = f2bf(acc[im][in][1]);
        pk.z = f2bf(acc[im][in][2]); pk.w = f2bf(acc[im][in][3]);
        *(ushort4*)&O[((size_t)(b * HH + h) * DKK + dk) * SS + s] = pk;
      }
  } else {
#pragma unroll
    for (int im = 0; im < 4; ++im)
#pragma unroll
      for (int in = 0; in < 4; ++in) {
        const int n = n0 + wc * 64 + in * 16 + lr;
        const int h = n >> 6, dk = n & 63;
#pragma unroll
        for (int i = 0; i < 4; ++i) {
          const int m = m0 + wr * 64 + im * 16 + qd * 4 + i;
          const int b = m >> 11, s = m & 2047;
          O[((size_t)(b * HH + h) * SS + s) * DKK + dk] = f2bf(acc[im][in][i]);
        }
      }
  }
}

// ---------------------------------------------------------------------------
// Kernel 2: causal flash attention, S^T orientation (q in lane dim).
// Block = (pair p, head, b): q-tiles p and 31-p -> exactly 33 kv-iters.
// S^T = K·Q^T (A=K, B=Q); O^T = V^T·P^T with K-permutation pi folded into the
// V-side LDS reads so P's C-frags are consumed in place (zero P traffic).
// ---------------------------------------------------------------------------
__global__ __launch_bounds__(256) void flash_attn(
    const unsigned short* __restrict__ Qm, const unsigned short* __restrict__ Km,
    const unsigned short* __restrict__ Vt, unsigned short* __restrict__ Xc) {
  __shared__ unsigned short Kl[2][4096];
  __shared__ unsigned short Vl[2][4096];
  const int p = blockIdx.x, head = blockIdx.y, b = blockIdx.z;
  const int tid = threadIdx.x, w = tid >> 6, l = tid & 63, lr = l & 15, qd = l >> 4;
  const size_t bh = (size_t)(b * HH + head);
  const unsigned short* Qb = Qm + bh * SS * DKK;
  const unsigned short* Kb = Km + bh * SS * DKK;
  const unsigned short* Vb = Vt + bh * DKK * SS;

  // this wave's 2-of-8 staging sub-tiles (for both K and V^T)
  const int sK0 = w, sK1 = w + 4;
  // V^T A-frag b64 offsets (ushort units), per (mt,kh) slot
  const int loOff = ((qd >> 1) * 16 + lr) * 8 + (qd & 1) * 4;
  const int hiOff = ((2 + (qd >> 1)) * 16 + lr) * 8 + (qd & 1) * 4;

#pragma unroll 1
  for (int si = 0; si < 2; ++si) {
    const int qt = si ? (31 - p) : p;
    const int q0 = qt * 64;
    const int nkv = qt + 1;
    const int qrow = q0 + w * 16 + lr;  // this lane's q (Sᵀ col = lane&15)

    // Q B-frags (lane n = q, k = dk): 16B rows, kept in regs all segment
    short8 qf0 = *(const short8*)&Qb[(size_t)qrow * DKK + qd * 8];
    short8 qf1 = *(const short8*)&Qb[(size_t)qrow * DKK + 32 + qd * 8];

    f32x4 o[4];  // O^T C-frags: row = dk (mt*16+qd*4+i), col = q (= lr)
#pragma unroll
    for (int i = 0; i < 4; ++i) o[i] = fzero();
    float m2 = -3e38f, ll = 0.f;  // per-lane online state for q = qrow

    __syncthreads();  // prior segment's LDS reads complete before buf0 overwrite
    {  // prefetch kv=0 -> buf0
      gld16(&Kb[(size_t)((sK0 >> 1) * 16 + lr) * DKK + (sK0 & 1) * 32 + qd * 8],
            &Kl[0][sK0 * 512]);
      gld16(&Kb[(size_t)((sK1 >> 1) * 16 + lr) * DKK + (sK1 & 1) * 32 + qd * 8],
            &Kl[0][sK1 * 512]);
      gld16(&Vb[(size_t)((sK0 >> 1) * 16 + lr) * SS + (sK0 & 1) * 32 + qd * 8],
            &Vl[0][sK0 * 512]);
      gld16(&Vb[(size_t)((sK1 >> 1) * 16 + lr) * SS + (sK1 & 1) * 32 + qd * 8],
            &Vl[0][sK1 * 512]);
    }

#pragma unroll 1
    for (int kv = 0; kv < nkv; ++kv) {
      __syncthreads();  // drains prefetch(kv); fences buffer reuse
      const int cur = kv & 1;
      if (kv + 1 < nkv) {  // prefetch kv+1 into the other buffer
        const int kv0n = (kv + 1) * 64;
        gld16(&Kb[(size_t)(kv0n + (sK0 >> 1) * 16 + lr) * DKK + (sK0 & 1) * 32 + qd * 8],
              &Kl[cur ^ 1][sK0 * 512]);
        gld16(&Kb[(size_t)(kv0n + (sK1 >> 1) * 16 + lr) * DKK + (sK1 & 1) * 32 + qd * 8],
              &Kl[cur ^ 1][sK1 * 512]);
        gld16(&Vb[(size_t)((sK0 >> 1) * 16 + lr) * SS + kv0n + (sK0 & 1) * 32 + qd * 8],
              &Vl[cur ^ 1][sK0 * 512]);
        gld16(&Vb[(size_t)((sK1 >> 1) * 16 + lr) * SS + kv0n + (sK1 & 1) * 32 + qd * 8],
              &Vl[cur ^ 1][sK1 * 512]);
      }

      const int kv0 = kv * 64;
      // S^T = K Q^T : C-frags [kv16][q16], rows kv = qd*4+i, cols q = lr
      f32x4 sc[4];
#pragma unroll
      for (int nt = 0; nt < 4; ++nt) {
        short8 kf0 = *(const short8*)&Kl[cur][(nt * 2 + 0) * 512 + l * 8];
        short8 kf1 = *(const short8*)&Kl[cur][(nt * 2 + 1) * 512 + l * 8];
        f32x4 zz = fzero();
        zz = __builtin_amdgcn_mfma_f32_16x16x32_bf16(kf0, qf0, zz, 0, 0, 0);
        sc[nt] = __builtin_amdgcn_mfma_f32_16x16x32_bf16(kf1, qf1, zz, 0, 0, 0);
      }
      const bool diag = (kv == qt);
#pragma unroll
      for (int nt = 0; nt < 4; ++nt)
#pragma unroll
        for (int i = 0; i < 4; ++i) {
          float vv = sc[nt][i] * 0.125f;  // 1/sqrt(64)
          if (diag) {
            const int kvi = kv0 + nt * 16 + qd * 4 + i;
            if (kvi > qrow) vv = -3e38f;
          }
          sc[nt][i] = vv;
        }

      // online softmax for q = qrow: 16 in-lane values + 2 cross-quad shuffles
      float mx = sc[0][0];
#pragma unroll
      for (int nt = 0; nt < 4; ++nt)
#pragma unroll
        for (int i = 0; i < 4; ++i) mx = fmaxf(mx, sc[nt][i]);
      mx = fmaxf(mx, __shfl_xor(mx, 16));
      mx = fmaxf(mx, __shfl_xor(mx, 32));
      const float mnew = fmaxf(m2, mx);
      const float alpha = __expf(m2 - mnew);
      m2 = mnew;
      float rs = 0.f;
#pragma unroll
      for (int nt = 0; nt < 4; ++nt)
#pragma unroll
        for (int i = 0; i < 4; ++i) {
          const float pp = __expf(sc[nt][i] - mnew);
          sc[nt][i] = pp;
          rs += pp;
        }
      rs += __shfl_xor(rs, 16);
      rs += __shfl_xor(rs, 32);
      ll = ll * alpha + rs;
#pragma unroll
      for (int mt = 0; mt < 4; ++mt) o[mt] *= alpha;

      // pack P pairs: pd[f][p] = bf16x2 of (sc[f][2p], sc[f][2p+1])
      unsigned int pd[4][2];
#pragma unroll
      for (int f = 0; f < 4; ++f) {
        pd[f][0] = pkbf(sc[f][0], sc[f][1]);
        pd[f][1] = pkbf(sc[f][2], sc[f][3]);
      }

      // O^T += V^T P^T, K-order pi(quad*8+j) = (2kh+(j>>2))*16 + quad*4 + (j&3)
#pragma unroll
      for (int kh = 0; kh < 2; ++kh) {
        short8 bfr = mk8u(pd[2 * kh][0], pd[2 * kh][1],
                          pd[2 * kh + 1][0], pd[2 * kh + 1][1]);
#pragma unroll
        for (int mt = 0; mt < 4; ++mt) {
          const int sbase = (mt * 2 + kh) * 512;
          const unsigned long long lo =
              *(const unsigned long long*)&Vl[cur][sbase + loOff];
          const unsigned long long hi =
              *(const unsigned long long*)&Vl[cur][sbase + hiOff];
          o[mt] = __builtin_amdgcn_mfma_f32_16x16x32_bf16(mk8q(lo, hi), bfr,
                                                          o[mt], 0, 0, 0);
        }
      }
    }

    // normalize + write bf16 [B,S,D]; lane's column q = qrow, rows = dk
    const float inv = 1.0f / ll;
    unsigned short* Xr = Xc + ((size_t)b * SS + qrow) * DD + (size_t)head * DKK;
#pragma unroll
    for (int mt = 0; mt < 4; ++mt)
#pragma unroll
      for (int i = 0; i < 4; ++i)
        Xr[mt * 16 + qd * 4 + i] = f2bf(o[mt][i] * inv);
  }
}

// ---------------------------------------------------------------------------
// Kernel 3: out = Xc @ w_o^T, fp32 epilogue straight to d_out
// ---------------------------------------------------------------------------
__global__ __launch_bounds__(256) void out_gemm(
    const unsigned short* __restrict__ Xc, const unsigned short* __restrict__ Wo,
    float* __restrict__ out) {
  __shared__ unsigned short ldsA[8192];
  __shared__ unsigned short ldsB[8192];
  const int m0 = blockIdx.x * 128, n0 = blockIdx.y * 128;
  f32x4 acc[4][4];
  gemm_tile(Xc, Wo, ldsA, ldsB, m0, n0, acc);

  const int tid = threadIdx.x;
  const int w = tid >> 6, l = tid & 63, lr = l & 15, qd = l >> 4;
  const int wr = w >> 1, wc = w & 1;
#pragma unroll
  for (int im = 0; im < 4; ++im)
#pragma unroll
    for (int in = 0; in < 4; ++in) {
      const int n = n0 + wc * 64 + in * 16 + lr;
#pragma unroll
      for (int i = 0; i < 4; ++i) {
        const int m = m0 + wr * 64 + im * 16 + qd * 4 + i;
        out[(size_t)m * DD + n] = acc[im][in][i];
      }
    }
}

// ---------------------------------------------------------------------------
extern "C" void kernel_launch(void* const* d_in, const int* in_sizes, int n_in,
                              void* d_out, int out_size, void* d_ws, size_t ws_size,
                              hipStream_t stream) {
  (void)in_sizes; (void)n_in; (void)out_size; (void)ws_size;
  const float* q  = (const float*)d_in[0];
  const float* k  = (const float*)d_in[1];
  const float* v  = (const float*)d_in[2];
  const float* wq = (const float*)d_in[4];
  const float* wk = (const float*)d_in[5];
  const float* wv = (const float*)d_in[6];
  const float* wo = (const float*)d_in[7];
  unsigned short* ws = (unsigned short*)d_ws;
  float* out = (float*)d_out;

  convert_all<<<dim3(16384), dim3(256), 0, stream>>>(q, k, v, wq, wk, wv, wo, ws);
  proj_gemm<<<dim3(32, 8, 3), dim3(256), 0, stream>>>(ws);
  flash_attn<<<dim3(16, 16, 2), dim3(256), 0, stream>>>(ws + OFF_QM, ws + OFF_KM,
                                                        ws + OFF_VM, ws + OFF_XC);
  out_gemm<<<dim3(32, 8), dim3(256), 0, stream>>>(ws + OFF_XC, ws + OFF_WO, out);
}